// Round 5
// baseline (55.882 us; speedup 1.0000x reference)
//
#include <hip/hip_runtime.h>
#include <stdint.h>

// PropNet cost-volume via bf16 MFMA — single fused kernel.
// y is transposed fp32->bf16 PER BLOCK via an LDS staging tile (coalesced
// float4 window-row loads -> F[32ch][192px] -> swizzled bf16 pack), so no
// prepass, no workspace round-trip, one dispatch.
// N=2, C=256, H=W=96, max_distance=4 (window 9x9), num_class=124.
#define Nn 2
#define Cc 256
#define Hh 96
#define Ww 96
#define HW (Hh * Ww)
#define MD 4
#define NC 124
#define TH 4                    // dest tile rows
#define TWD 8                   // dest tile cols
#define NQ (TH * TWD)           // 32 dest pixels (MFMA M)
#define SH (TH + 2 * MD)        // 12 window rows
#define SWD (TWD + 2 * MD)      // 16 window cols
#define NS (SH * SWD)           // 192 src pixels (MFMA N)
#define BLK 256                 // 4 waves
#define NBW (Ww / TWD)          // 12
#define NBH (Hh / TH)           // 24
#define NBLK (Nn * NBH * NBW)   // 576 blocks (divisible by 8)
#define YROW 64                 // bytes per pixel row in a chunk (32 ch * 2B)
#define XOFF (NS * YROW)        // 12288: x region offset inside B buffer
#define BUFSZ (XOFF + NQ * YROW) // 14336 bytes
#define TBL (NQ * NC)           // 3968 table entries (15872B <= sizeof(F))

typedef short short8 __attribute__((ext_vector_type(8)));
typedef float f32x4 __attribute__((ext_vector_type(4)));

// Monotone float -> uint mapping so unsigned min == float min.
__device__ __forceinline__ unsigned fmap(float f) {
    unsigned b = __float_as_uint(f);
    return (b & 0x80000000u) ? ~b : (b | 0x80000000u);
}
__device__ __forceinline__ float funmap(unsigned u) {
    unsigned b = (u & 0x80000000u) ? (u & 0x7fffffffu) : ~u;
    return __uint_as_float(b);
}
// XOR-swizzled byte offset of 16B ch-slot `slot` in pixel-row `row`.
// Used by BOTH the pack writes and the fragment reads -> always consistent.
__device__ __forceinline__ int swz(int row, int slot) {
    return row * YROW + ((slot ^ ((row >> 1) & 3)) << 4);
}

__global__ __launch_bounds__(BLK) void propnet_fused(
    const float* __restrict__ x, const float* __restrict__ y,
    const int* __restrict__ labels, float* __restrict__ out)
{
    __shared__ __align__(16) float F[32 * NS];            // 24576B fp32 y staging
    __shared__ __align__(16) unsigned char B[BUFSZ];      // bf16 MFMA operands
    __shared__ float y2s[NS];
    __shared__ float x2s[NQ];
    __shared__ int   labs[NS];
    unsigned* table = (unsigned*)F;   // aliased after the K-loop

    const int t = threadIdx.x;

    // XCD-aware bijective swizzle: contiguous 72-block chunk per XCD.
    const int orig = blockIdx.x;
    const int lin  = (orig & 7) * (NBLK / 8) + (orig >> 3);
    const int n    = lin / (NBH * NBW);
    const int rem  = lin - n * (NBH * NBW);
    const int h0   = (rem / NBW) * TH;
    const int w0   = (rem % NBW) * TWD;
    const size_t nb = (size_t)n * Cc * HW;

    if (t < NS) {
        const int sr = t >> 4, sc = t & 15;
        const int gh = h0 - MD + sr, gw = w0 - MD + sc;
        const bool ok = (gh >= 0) && (gh < Hh) && (gw >= 0) && (gw < Ww);
        labs[t] = ok ? labels[(size_t)n * HW + gh * Ww + gw] : -1;  // -1: excluded
        y2s[t]  = 0.f;
    }
    if (t < NQ) x2s[t] = 0.f;

    // ---- y load descriptors: 1536 tasks = (ch 0..31, row g 0..11, seg 0..3).
    // Window cols w0-4..w0+11 = four 4-px (16B) segments, each all-valid or
    // all-invalid; invalid segs clamp in-range (garbage excluded via labs).
    const float* ysrc6[6]; int fwb[6];
#pragma unroll
    for (int k = 0; k < 6; ++k) {
        const int task = t + 256 * k;
        const int ch = task / 48;
        const int r  = task - ch * 48;
        const int g  = r >> 2;
        const int sg = r & 3;
        const int gh = min(max(h0 - MD + g, 0), Hh - 1);
        const int ws = min(max(w0 - MD + sg * 4, 0), Ww - 4);
        ysrc6[k] = y + nb + (size_t)ch * HW + (size_t)gh * Ww + ws;
        fwb[k]   = ch * (NS * 4) + g * 64 + sg * 16;   // F byte offset [ch][g*16+sg*4]
    }
    float4 yv[6];
    auto yload = [&](int c) {
        const size_t coff = (size_t)(c * 32) * HW;
#pragma unroll
        for (int k = 0; k < 6; ++k) yv[k] = *(const float4*)(ysrc6[k] + coff);
    };
    auto fwrite = [&]() {
#pragma unroll
        for (int k = 0; k < 6; ++k) *(float4*)((char*)F + fwb[k]) = yv[k];
    };

    // ---- pack descriptors: 768 tasks = (pix 0..191, slot 0..3), 3/thread.
    int ppix[3], pwb[3]; const float* pcol[3];
#pragma unroll
    for (int i = 0; i < 3; ++i) {
        const int task = t + 256 * i;
        const int pix  = task % NS;
        const int slot = task / NS;
        ppix[i] = pix;
        pwb[i]  = swz(pix, slot);
        pcol[i] = F + slot * 8 * NS + pix;   // 8 consecutive-ch reads, stride NS
    }
    float ysq[3] = {0.f, 0.f, 0.f};
    auto packY = [&]() {
#pragma unroll
        for (int i = 0; i < 3; ++i) {
            float v[8];
#pragma unroll
            for (int j = 0; j < 8; ++j) v[j] = pcol[i][j * NS];
            unsigned pk[4];
#pragma unroll
            for (int j = 0; j < 4; ++j) {
                ysq[i] = fmaf(v[2*j],   v[2*j],   ysq[i]);
                ysq[i] = fmaf(v[2*j+1], v[2*j+1], ysq[i]);
                pk[j] = (__float_as_uint(v[2*j]) >> 16) |
                        (__float_as_uint(v[2*j+1]) & 0xffff0000u);
            }
            *(uint4*)(B + pwb[i]) = make_uint4(pk[0], pk[1], pk[2], pk[3]);
        }
    };

    // ---- x path: reg-staged fp32 (read once); loads fly over MFMAs (T14).
    const bool xw = (t < 128);
    const float* xptr = x; int xoffw = 0, xpix = 0;
    if (xw) {
        xpix = t & 31;
        const int grp = t >> 5;
        const int qr = xpix >> 3, qc = xpix & 7;
        xptr = x + nb + (size_t)(grp * 8) * HW + (size_t)(h0 + qr) * Ww + (w0 + qc);
        xoffw = XOFF + swz(xpix, grp);
    }
    float xsq = 0.f;
    float xv[8];
    auto xload = [&](int c) {
        if (!xw) return;
        const float* p = xptr + (size_t)(c * 32) * HW;
#pragma unroll
        for (int j = 0; j < 8; ++j) xv[j] = p[(size_t)j * HW];
    };
    auto xwrite = [&]() {
        if (!xw) return;
        unsigned pk[4];
#pragma unroll
        for (int j = 0; j < 4; ++j) {
            xsq = fmaf(xv[2*j],   xv[2*j],   xsq);
            xsq = fmaf(xv[2*j+1], xv[2*j+1], xsq);
            pk[j] = (__float_as_uint(xv[2*j]) >> 16) |
                    (__float_as_uint(xv[2*j+1]) & 0xffff0000u);
        }
        *(uint4*)(B + xoffw) = make_uint4(pk[0], pk[1], pk[2], pk[3]);
    };

    // ---- MFMA fragments ----
    const int lane = t & 63;
    const int wid  = t >> 6;
    const int l15  = lane & 15;
    const int lg   = lane >> 4;       // 8-ch k-slot
    int aoff[2], boff[3];
#pragma unroll
    for (int mf = 0; mf < 2; ++mf) aoff[mf] = XOFF + swz(mf * 16 + l15, lg);
#pragma unroll
    for (int nf = 0; nf < 3; ++nf) boff[nf] = swz(wid * 48 + nf * 16 + l15, lg);

    f32x4 acc[2][3];
#pragma unroll
    for (int mf = 0; mf < 2; ++mf)
#pragma unroll
        for (int nf = 0; nf < 3; ++nf)
            acc[mf][nf] = (f32x4){0.f, 0.f, 0.f, 0.f};

    auto compute = [&]() {
        short8 a[2], b[3];
#pragma unroll
        for (int mf = 0; mf < 2; ++mf) a[mf] = *(const short8*)(B + aoff[mf]);
#pragma unroll
        for (int nf = 0; nf < 3; ++nf) b[nf] = *(const short8*)(B + boff[nf]);
#pragma unroll
        for (int mf = 0; mf < 2; ++mf)
#pragma unroll
            for (int nf = 0; nf < 3; ++nf)
                acc[mf][nf] = __builtin_amdgcn_mfma_f32_16x16x32_bf16(
                    a[mf], b[nf], acc[mf][nf], 0, 0, 0);
    };

    // ---- K-loop: 8 chunks of 32 ch; per chunk: {loads->regs | MFMA} then
    // {F write, pack->B}. Single F + single B, 2 barriers per chunk.
    yload(0); xload(0);
    fwrite();
    __syncthreads();
    packY(); xwrite();
    __syncthreads();
    for (int c = 0; c < 8; ++c) {
        if (c < 7) { yload(c + 1); xload(c + 1); }  // regs; latency under MFMAs
        compute();                                   // chunk c from B
        if (c < 7) fwrite();                         // stage fp32 of chunk c+1
        __syncthreads();
        if (c < 7) { packY(); xwrite(); }            // B <- chunk c+1
        __syncthreads();
    }

    // ---- norms reduce; init tables (F dead now) ----
#pragma unroll
    for (int i = 0; i < 3; ++i) atomicAdd(&y2s[ppix[i]], ysq[i]);
    if (xw) atomicAdd(&x2s[xpix], xsq);
    for (int i = t; i < TBL; i += BLK) table[i] = 0xBF800000u;  // fmap(1.0f)
    __syncthreads();

    // ---- epilogue: d -> sigmoid -> label-masked min ----
    // C layout: col(n) = l&15, row(m) = (l>>4)*4 + reg.
#pragma unroll
    for (int mf = 0; mf < 2; ++mf) {
#pragma unroll
        for (int nf = 0; nf < 3; ++nf) {
#pragma unroll
            for (int r = 0; r < 4; ++r) {
                const int q = mf * 16 + lg * 4 + r;       // dest pixel 0..31
                const int s = wid * 48 + nf * 16 + l15;   // src pixel 0..191
                const int qr = q >> 3, qc = q & 7;
                const int sr = s >> 4, sc = s & 15;
                const int di = sr - qr, dj = sc - qc;
                const int lab = labs[s];
                if (di >= 0 && di <= 2 * MD && dj >= 0 && dj <= 2 * MD &&
                    lab >= 0 && lab < NC) {
                    const float d  = x2s[q] + y2s[s] - 2.0f * acc[mf][nf][r];
                    const float sg = 1.0f / (1.0f + __expf(-d));
                    atomicMin(&table[q * NC + lab], fmap(fmaf(2.0f, sg, -1.0f)));
                }
            }
        }
    }
    __syncthreads();

    // ---- write out[n][class][h0+qr][w0+qc] ----
    const size_t ob = (size_t)n * NC * HW;
    for (int i = t; i < TBL; i += BLK) {
        const int g = i >> 5;        // class
        const int q = i & 31;        // dest pixel
        const int qr = q >> 3, qc = q & 7;
        out[ob + (size_t)g * HW + (size_t)(h0 + qr) * Ww + (w0 + qc)] =
            funmap(table[q * NC + g]);
    }
}

extern "C" void kernel_launch(void* const* d_in, const int* in_sizes, int n_in,
                              void* d_out, int out_size, void* d_ws, size_t ws_size,
                              hipStream_t stream) {
    const float* x      = (const float*)d_in[0];
    const float* y      = (const float*)d_in[1];
    const int*   labels = (const int*)d_in[2];
    float*       out    = (float*)d_out;
    (void)in_sizes; (void)n_in; (void)out_size; (void)d_ws; (void)ws_size;

    propnet_fused<<<dim3(NBLK), dim3(BLK), 0, stream>>>(x, y, labels, out);
}

// Round 6
// 32.341 us; speedup vs baseline: 1.7279x; 1.7279x over previous
//
#include <hip/hip_runtime.h>
#include <stdint.h>

// PropNet cost-volume via bf16 MFMA — single fused kernel.
// y is staged per-block via global_load_lds DMA into an fp32 LDS tile
// (F[32ch][192px], linear in DMA task order), then packed to the swizzled
// bf16 MFMA operand buffer. No prepass, no workspace, no registers live
// across the MFMA phase (round-5's spill source).
// N=2, C=256, H=W=96, max_distance=4 (window 9x9), num_class=124.
#define Nn 2
#define Cc 256
#define Hh 96
#define Ww 96
#define HW (Hh * Ww)
#define MD 4
#define NC 124
#define TH 4                    // dest tile rows
#define TWD 8                   // dest tile cols
#define NQ (TH * TWD)           // 32 dest pixels (MFMA M)
#define SH (TH + 2 * MD)        // 12 window rows
#define SWD (TWD + 2 * MD)      // 16 window cols
#define NS (SH * SWD)           // 192 src pixels (MFMA N)
#define BLK 256                 // 4 waves
#define NBW (Ww / TWD)          // 12
#define NBH (Hh / TH)           // 24
#define NBLK (Nn * NBH * NBW)   // 576 blocks (divisible by 8)
#define YROW 64                 // bytes per pixel row in a chunk (32 ch * 2B)
#define XOFF (NS * YROW)        // 12288: x region offset inside B buffer
#define BUFSZ (XOFF + NQ * YROW) // 14336 bytes
#define TBL (NQ * NC)           // 3968 table entries (15872B <= sizeof(F))

typedef short short8 __attribute__((ext_vector_type(8)));
typedef float f32x4 __attribute__((ext_vector_type(4)));

// Monotone float -> uint mapping so unsigned min == float min.
__device__ __forceinline__ unsigned fmap(float f) {
    unsigned b = __float_as_uint(f);
    return (b & 0x80000000u) ? ~b : (b | 0x80000000u);
}
__device__ __forceinline__ float funmap(unsigned u) {
    unsigned b = (u & 0x80000000u) ? (u & 0x7fffffffu) : ~u;
    return __uint_as_float(b);
}
// XOR-swizzled byte offset of 16B ch-slot `slot` in pixel-row `row`.
// Used by BOTH the pack writes and the fragment reads -> always consistent.
__device__ __forceinline__ int swz(int row, int slot) {
    return row * YROW + ((slot ^ ((row >> 1) & 3)) << 4);
}

__global__ __launch_bounds__(BLK, 2) void propnet_fused(
    const float* __restrict__ x, const float* __restrict__ y,
    const int* __restrict__ labels, float* __restrict__ out)
{
    __shared__ __align__(16) float F[32 * NS];            // 24576B fp32 y staging
    __shared__ __align__(16) unsigned char B[BUFSZ];      // bf16 MFMA operands
    __shared__ float y2s[NS];
    __shared__ float x2s[NQ];
    __shared__ int   labs[NS];
    unsigned* table = (unsigned*)F;   // aliased after the K-loop

    const int t = threadIdx.x;

    // XCD-aware bijective swizzle: contiguous 72-block chunk per XCD.
    const int orig = blockIdx.x;
    const int lin  = (orig & 7) * (NBLK / 8) + (orig >> 3);
    const int n    = lin / (NBH * NBW);
    const int rem  = lin - n * (NBH * NBW);
    const int h0   = (rem / NBW) * TH;
    const int w0   = (rem % NBW) * TWD;
    const size_t nb = (size_t)n * Cc * HW;

    if (t < NS) {
        const int sr = t >> 4, sc = t & 15;
        const int gh = h0 - MD + sr, gw = w0 - MD + sc;
        const bool ok = (gh >= 0) && (gh < Hh) && (gw >= 0) && (gw < Ww);
        labs[t] = ok ? labels[(size_t)n * HW + gh * Ww + gw] : -1;  // -1: excluded
        y2s[t]  = 0.f;
    }
    if (t < NQ) x2s[t] = 0.f;

    const int lane = t & 63;
    const int wid  = t >> 6;

    // ---- y DMA descriptors. F is linear in task order (task = ch*48+g*4+sg,
    // 16B per task): per-wave inst m covers tasks [(wid*6+m)*64, +64), LDS
    // dest = F + (wid*6+m)*1024 (wave-uniform), global src per-lane.
    // Window cols = four 4-px (16B) segments, all-or-nothing valid at edges;
    // invalid rows/segs clamp in-range (garbage excluded via labs).
    unsigned yoff[6];
#pragma unroll
    for (int k = 0; k < 6; ++k) {
        const int task = (wid * 6 + k) * 64 + lane;
        const int ch = task / 48;
        const int r  = task - ch * 48;
        const int g  = r >> 2;
        const int sg = r & 3;
        const int gh = min(max(h0 - MD + g, 0), Hh - 1);
        const int ws = min(max(w0 - MD + sg * 4, 0), Ww - 4);
        yoff[k] = (unsigned)((ch * HW + gh * Ww + ws) * 4);   // bytes
    }
    const char* ybp = (const char*)(y + nb);
    auto stageF = [&](int c) {
        const size_t coff = (size_t)(c * 32) * HW * 4;
#pragma unroll
        for (int k = 0; k < 6; ++k)
            __builtin_amdgcn_global_load_lds(
                (const __attribute__((address_space(1))) unsigned int*)
                    (ybp + coff + yoff[k]),
                (__attribute__((address_space(3))) unsigned int*)
                    ((char*)F + (wid * 6 + k) * 1024),
                16, 0, 0);
    };

    // ---- pack descriptors: 768 tasks = (pix 0..191, slot 0..3), 3/thread.
    int ppix[3], pwb[3]; const float* pcol[3];
#pragma unroll
    for (int i = 0; i < 3; ++i) {
        const int task = t + 256 * i;
        const int pix  = task % NS;
        const int slot = task / NS;
        ppix[i] = pix;
        pwb[i]  = swz(pix, slot);
        pcol[i] = F + slot * 8 * NS + pix;   // 8 ch reads, stride NS (2-way banks)
    }
    float ysq[3] = {0.f, 0.f, 0.f};
    auto packY = [&]() {
#pragma unroll
        for (int i = 0; i < 3; ++i) {
            float v[8];
#pragma unroll
            for (int j = 0; j < 8; ++j) v[j] = pcol[i][j * NS];
            unsigned pk[4];
#pragma unroll
            for (int j = 0; j < 4; ++j) {
                ysq[i] = fmaf(v[2*j],   v[2*j],   ysq[i]);
                ysq[i] = fmaf(v[2*j+1], v[2*j+1], ysq[i]);
                pk[j] = (__float_as_uint(v[2*j]) >> 16) |
                        (__float_as_uint(v[2*j+1]) & 0xffff0000u);
            }
            *(uint4*)(B + pwb[i]) = make_uint4(pk[0], pk[1], pk[2], pk[3]);
        }
    };

    // ---- x path: reg-staged fp32 (read once, 8 regs); loads fly over MFMAs.
    const bool xw = (t < 128);
    const float* xptr = x; int xoffw = 0, xpix = 0;
    if (xw) {
        xpix = t & 31;
        const int grp = t >> 5;
        const int qr = xpix >> 3, qc = xpix & 7;
        xptr = x + nb + (size_t)(grp * 8) * HW + (size_t)(h0 + qr) * Ww + (w0 + qc);
        xoffw = XOFF + swz(xpix, grp);
    }
    float xsq = 0.f;
    float xv[8];
    auto xload = [&](int c) {
        if (!xw) return;
        const float* p = xptr + (size_t)(c * 32) * HW;
#pragma unroll
        for (int j = 0; j < 8; ++j) xv[j] = p[(size_t)j * HW];
    };
    auto xwrite = [&]() {
        if (!xw) return;
        unsigned pk[4];
#pragma unroll
        for (int j = 0; j < 4; ++j) {
            xsq = fmaf(xv[2*j],   xv[2*j],   xsq);
            xsq = fmaf(xv[2*j+1], xv[2*j+1], xsq);
            pk[j] = (__float_as_uint(xv[2*j]) >> 16) |
                    (__float_as_uint(xv[2*j+1]) & 0xffff0000u);
        }
        *(uint4*)(B + xoffw) = make_uint4(pk[0], pk[1], pk[2], pk[3]);
    };

    // ---- MFMA fragments ----
    const int l15 = lane & 15;
    const int lg  = lane >> 4;        // 8-ch k-slot
    int aoff[2], boff[3];
#pragma unroll
    for (int mf = 0; mf < 2; ++mf) aoff[mf] = XOFF + swz(mf * 16 + l15, lg);
#pragma unroll
    for (int nf = 0; nf < 3; ++nf) boff[nf] = swz(wid * 48 + nf * 16 + l15, lg);

    f32x4 acc[2][3];
#pragma unroll
    for (int mf = 0; mf < 2; ++mf)
#pragma unroll
        for (int nf = 0; nf < 3; ++nf)
            acc[mf][nf] = (f32x4){0.f, 0.f, 0.f, 0.f};

    auto compute = [&]() {
        short8 a[2], b[3];
#pragma unroll
        for (int mf = 0; mf < 2; ++mf) a[mf] = *(const short8*)(B + aoff[mf]);
#pragma unroll
        for (int nf = 0; nf < 3; ++nf) b[nf] = *(const short8*)(B + boff[nf]);
#pragma unroll
        for (int mf = 0; mf < 2; ++mf)
#pragma unroll
            for (int nf = 0; nf < 3; ++nf)
                acc[mf][nf] = __builtin_amdgcn_mfma_f32_16x16x32_bf16(
                    a[mf], b[nf], acc[mf][nf], 0, 0, 0);
    };

    // ---- K-loop: 8 chunks of 32 ch. Per chunk:
    //   {F-DMA(c+1) + x reg-loads fly | MFMA on B(c)} -> barrier (vmcnt drain)
    //   {packY F->B, xwrite}                          -> barrier
    stageF(0); xload(0);
    __syncthreads();            // F(0) ready
    packY(); xwrite();
    __syncthreads();            // B(0) ready
    for (int c = 0; c < 8; ++c) {
        if (c < 7) { stageF(c + 1); xload(c + 1); }
        compute();
        __syncthreads();        // F(c+1) landed; all waves done reading B
        if (c < 7) { packY(); xwrite(); }
        __syncthreads();        // B(c+1) ready
    }

    // ---- norms reduce; init tables (F dead now) ----
#pragma unroll
    for (int i = 0; i < 3; ++i) atomicAdd(&y2s[ppix[i]], ysq[i]);
    if (xw) atomicAdd(&x2s[xpix], xsq);
    for (int i = t; i < TBL; i += BLK) table[i] = 0xBF800000u;  // fmap(1.0f)
    __syncthreads();

    // ---- epilogue: d -> sigmoid -> label-masked min ----
    // C layout: col(n) = l&15, row(m) = (l>>4)*4 + reg.
#pragma unroll
    for (int mf = 0; mf < 2; ++mf) {
#pragma unroll
        for (int nf = 0; nf < 3; ++nf) {
#pragma unroll
            for (int r = 0; r < 4; ++r) {
                const int q = mf * 16 + lg * 4 + r;       // dest pixel 0..31
                const int s = wid * 48 + nf * 16 + l15;   // src pixel 0..191
                const int qr = q >> 3, qc = q & 7;
                const int sr = s >> 4, sc = s & 15;
                const int di = sr - qr, dj = sc - qc;
                const int lab = labs[s];
                if (di >= 0 && di <= 2 * MD && dj >= 0 && dj <= 2 * MD &&
                    lab >= 0 && lab < NC) {
                    const float d  = x2s[q] + y2s[s] - 2.0f * acc[mf][nf][r];
                    const float sg = 1.0f / (1.0f + __expf(-d));
                    atomicMin(&table[q * NC + lab], fmap(fmaf(2.0f, sg, -1.0f)));
                }
            }
        }
    }
    __syncthreads();

    // ---- write out[n][class][h0+qr][w0+qc] ----
    const size_t ob = (size_t)n * NC * HW;
    for (int i = t; i < TBL; i += BLK) {
        const int g = i >> 5;        // class
        const int q = i & 31;        // dest pixel
        const int qr = q >> 3, qc = q & 7;
        out[ob + (size_t)g * HW + (size_t)(h0 + qr) * Ww + (w0 + qc)] =
            funmap(table[q * NC + g]);
    }
}

extern "C" void kernel_launch(void* const* d_in, const int* in_sizes, int n_in,
                              void* d_out, int out_size, void* d_ws, size_t ws_size,
                              hipStream_t stream) {
    const float* x      = (const float*)d_in[0];
    const float* y      = (const float*)d_in[1];
    const int*   labels = (const int*)d_in[2];
    float*       out    = (float*)d_out;
    (void)in_sizes; (void)n_in; (void)out_size; (void)d_ws; (void)ws_size;

    propnet_fused<<<dim3(NBLK), dim3(BLK), 0, stream>>>(x, y, labels, out);
}

// Round 7
// 31.130 us; speedup vs baseline: 1.7951x; 1.0389x over previous
//
#include <hip/hip_runtime.h>
#include <stdint.h>

// PropNet cost-volume via bf16 MFMA — single fused kernel, all global reads
// in the K-loop via global_load_lds DMA (y AND x), 8 waves/block for MLP.
// N=2, C=256, H=W=96, max_distance=4 (window 9x9), num_class=124.
#define Nn 2
#define Cc 256
#define Hh 96
#define Ww 96
#define HW (Hh * Ww)
#define MD 4
#define NC 124
#define TH 4                    // dest tile rows
#define TWD 8                   // dest tile cols
#define NQ (TH * TWD)           // 32 dest pixels (MFMA M)
#define SH (TH + 2 * MD)        // 12 window rows
#define SWD (TWD + 2 * MD)      // 16 window cols
#define NS (SH * SWD)           // 192 src pixels (MFMA N)
#define BLK 512                 // 8 waves
#define NBW (Ww / TWD)          // 12
#define NBH (Hh / TH)           // 24
#define NBLK (Nn * NBH * NBW)   // 576 blocks (divisible by 8)
#define YROW 64                 // bytes per pixel row in a chunk (32 ch * 2B)
#define XOFF (NS * YROW)        // 12288: x region offset inside B buffer
#define BUFSZ (XOFF + NQ * YROW) // 14336 bytes
#define TBL (NQ * NC)           // 3968 table entries (15872B <= F bytes)
#define FW (32 * NS)            // 6144 words: fp32 y staging
#define XFW (32 * NQ)           // 1024 words: fp32 x staging
#define NPK (NS * 4 + NQ * 4)   // 896 pack tasks (y 768 + x 128)

typedef short short8 __attribute__((ext_vector_type(8)));
typedef float f32x4 __attribute__((ext_vector_type(4)));

// Monotone float -> uint mapping so unsigned min == float min.
__device__ __forceinline__ unsigned fmap(float f) {
    unsigned b = __float_as_uint(f);
    return (b & 0x80000000u) ? ~b : (b | 0x80000000u);
}
__device__ __forceinline__ float funmap(unsigned u) {
    unsigned b = (u & 0x80000000u) ? (u & 0x7fffffffu) : ~u;
    return __uint_as_float(b);
}
// XOR-swizzled byte offset of 16B ch-slot `slot` in pixel-row `row`.
// Used by BOTH the pack writes and the fragment reads -> always consistent.
__device__ __forceinline__ int swz(int row, int slot) {
    return row * YROW + ((slot ^ ((row >> 1) & 3)) << 4);
}

__global__ __launch_bounds__(BLK, 6) void propnet_fused(
    const float* __restrict__ x, const float* __restrict__ y,
    const int* __restrict__ labels, float* __restrict__ out)
{
    __shared__ __align__(16) float FX[FW + XFW];          // 28KB fp32 staging (y then x)
    __shared__ __align__(16) unsigned char B[BUFSZ];      // bf16 MFMA operands
    __shared__ float y2s[NS];
    __shared__ float x2s[NQ];
    __shared__ int   labs[NS];
    unsigned* table = (unsigned*)FX;   // aliased after the K-loop

    const int t = threadIdx.x;

    // XCD-aware bijective swizzle: contiguous 72-block chunk per XCD.
    const int orig = blockIdx.x;
    const int lin  = (orig & 7) * (NBLK / 8) + (orig >> 3);
    const int n    = lin / (NBH * NBW);
    const int rem  = lin - n * (NBH * NBW);
    const int h0   = (rem / NBW) * TH;
    const int w0   = (rem % NBW) * TWD;
    const size_t nb = (size_t)n * Cc * HW;

    if (t < NS) {
        const int sr = t >> 4, sc = t & 15;
        const int gh = h0 - MD + sr, gw = w0 - MD + sc;
        const bool ok = (gh >= 0) && (gh < Hh) && (gw >= 0) && (gw < Ww);
        labs[t] = ok ? labels[(size_t)n * HW + gh * Ww + gw] : -1;  // -1: excluded
        y2s[t]  = 0.f;
    }
    if (t < NQ) x2s[t] = 0.f;

    const int lane = t & 63;
    const int wid  = t >> 6;          // 0..7

    // ---- y DMA: 24 insts (3/wave). F linear in task order (task = ch*48 +
    // g*4 + sg, 16B each) -> F[ch][pix]. Window cols = four 16B segments,
    // all-or-nothing valid; invalid rows/segs clamp (excluded via labs).
    unsigned yoff[3];
#pragma unroll
    for (int k = 0; k < 3; ++k) {
        const int task = (wid * 3 + k) * 64 + lane;
        const int ch = task / 48;
        const int r  = task - ch * 48;
        const int g  = r >> 2;
        const int sg = r & 3;
        const int gh = min(max(h0 - MD + g, 0), Hh - 1);
        const int ws = min(max(w0 - MD + sg * 4, 0), Ww - 4);
        yoff[k] = (unsigned)((ch * HW + gh * Ww + ws) * 4);   // bytes
    }
    // ---- x DMA: 4 insts (waves 0..3, 1 each). Xf[ch][p] linear, p == dest
    // pixel q (p = seg*4+idx = qr*8+qc). All segments in-bounds.
    unsigned xoff = 0;
    if (wid < 4) {
        const int task = wid * 64 + lane;          // 0..255
        const int ch  = task >> 3;
        const int seg = task & 7;
        xoff = (unsigned)((ch * HW + (h0 + (seg >> 1)) * Ww + w0 + (seg & 1) * 4) * 4);
    }
    const char* ybp = (const char*)(y + nb);
    const char* xbp = (const char*)(x + nb);
    auto stage = [&](int c) {
        const size_t coff = (size_t)(c * 32) * HW * 4;
#pragma unroll
        for (int k = 0; k < 3; ++k)
            __builtin_amdgcn_global_load_lds(
                (const __attribute__((address_space(1))) unsigned int*)
                    (ybp + coff + yoff[k]),
                (__attribute__((address_space(3))) unsigned int*)
                    ((char*)FX + (wid * 3 + k) * 1024),
                16, 0, 0);
        if (wid < 4)
            __builtin_amdgcn_global_load_lds(
                (const __attribute__((address_space(1))) unsigned int*)
                    (xbp + coff + xoff),
                (__attribute__((address_space(3))) unsigned int*)
                    ((char*)FX + FW * 4 + wid * 1024),
                16, 0, 0);
    };

    // ---- pack descriptors: 896 tasks (y: pix 0..191 x slot 0..3; x: px x slot).
    bool pvalid[2], pisy[2]; int ppix[2], pwb[2], pstr[2]; const float* pcol[2];
#pragma unroll
    for (int i = 0; i < 2; ++i) {
        const int task = t + BLK * i;
        pvalid[i] = task < NPK;
        pisy[i]   = task < NS * 4;
        if (pisy[i]) {
            const int pix  = task % NS;
            const int slot = task / NS;
            ppix[i] = pix;
            pwb[i]  = swz(pix, slot);
            pcol[i] = FX + slot * 8 * NS + pix;    // stride NS words (2-way banks)
            pstr[i] = NS;
        } else {
            const int u    = (task - NS * 4) & 127;
            const int px   = u & 31;
            const int slot = u >> 5;
            ppix[i] = px;
            pwb[i]  = XOFF + swz(px, slot);
            pcol[i] = FX + FW + slot * 8 * NQ + px; // stride 32 words (2-way banks)
            pstr[i] = NQ;
        }
    }
    float psq[2] = {0.f, 0.f};
    auto pack = [&]() {
#pragma unroll
        for (int i = 0; i < 2; ++i) {
            if (!pvalid[i]) continue;
            float v[8];
#pragma unroll
            for (int j = 0; j < 8; ++j) v[j] = pcol[i][j * pstr[i]];
            unsigned pk[4];
#pragma unroll
            for (int j = 0; j < 4; ++j) {
                psq[i] = fmaf(v[2*j],   v[2*j],   psq[i]);
                psq[i] = fmaf(v[2*j+1], v[2*j+1], psq[i]);
                pk[j] = (__float_as_uint(v[2*j]) >> 16) |
                        (__float_as_uint(v[2*j+1]) & 0xffff0000u);
            }
            *(uint4*)(B + pwb[i]) = make_uint4(pk[0], pk[1], pk[2], pk[3]);
        }
    };

    // ---- MFMA fragments: wave = M-half (wid>>2) x N-quarter (wid&3). ----
    const int l15 = lane & 15;
    const int lg  = lane >> 4;        // 8-ch k-slot
    const int aoff = XOFF + swz((wid >> 2) * 16 + l15, lg);
    int boff[3];
#pragma unroll
    for (int nf = 0; nf < 3; ++nf)
        boff[nf] = swz((wid & 3) * 48 + nf * 16 + l15, lg);

    f32x4 acc[3];
#pragma unroll
    for (int nf = 0; nf < 3; ++nf) acc[nf] = (f32x4){0.f, 0.f, 0.f, 0.f};

    auto compute = [&]() {
        short8 a = *(const short8*)(B + aoff);
        short8 b[3];
#pragma unroll
        for (int nf = 0; nf < 3; ++nf) b[nf] = *(const short8*)(B + boff[nf]);
#pragma unroll
        for (int nf = 0; nf < 3; ++nf)
            acc[nf] = __builtin_amdgcn_mfma_f32_16x16x32_bf16(a, b[nf], acc[nf], 0, 0, 0);
    };

    // ---- K-loop: 8 chunks of 32 ch. Per chunk:
    //   {DMA(c+1) issues | MFMA on B(c)} -> barrier (vmcnt drained)
    //   {pack FX -> B(c+1)}              -> barrier
    stage(0);
    __syncthreads();            // FX(0) ready
    pack();
    __syncthreads();            // B(0) ready
    for (int c = 0; c < 8; ++c) {
        if (c < 7) stage(c + 1);
        compute();
        __syncthreads();        // FX(c+1) landed; all waves done reading B
        if (c < 7) pack();
        __syncthreads();        // B(c+1) ready
    }

    // ---- norms reduce; init tables (FX dead now) ----
#pragma unroll
    for (int i = 0; i < 2; ++i)
        if (pvalid[i]) atomicAdd(pisy[i] ? &y2s[ppix[i]] : &x2s[ppix[i]], psq[i]);
    for (int i = t; i < TBL; i += BLK) table[i] = 0xBF800000u;  // fmap(1.0f)
    __syncthreads();

    // ---- epilogue: d -> sigmoid -> label-masked min ----
    // C layout: col(n) = l&15, row(m) = (l>>4)*4 + reg.
#pragma unroll
    for (int nf = 0; nf < 3; ++nf) {
#pragma unroll
        for (int r = 0; r < 4; ++r) {
            const int q = (wid >> 2) * 16 + lg * 4 + r;       // dest pixel 0..31
            const int s = (wid & 3) * 48 + nf * 16 + l15;     // src pixel 0..191
            const int qr = q >> 3, qc = q & 7;
            const int sr = s >> 4, sc = s & 15;
            const int di = sr - qr, dj = sc - qc;
            const int lab = labs[s];
            if (di >= 0 && di <= 2 * MD && dj >= 0 && dj <= 2 * MD &&
                lab >= 0 && lab < NC) {
                const float d  = x2s[q] + y2s[s] - 2.0f * acc[nf][r];
                const float sg = 1.0f / (1.0f + __expf(-d));
                atomicMin(&table[q * NC + lab], fmap(fmaf(2.0f, sg, -1.0f)));
            }
        }
    }
    __syncthreads();

    // ---- write out[n][class][h0+qr][w0+qc] ----
    const size_t ob = (size_t)n * NC * HW;
    for (int i = t; i < TBL; i += BLK) {
        const int g = i >> 5;        // class
        const int q = i & 31;        // dest pixel
        const int qr = q >> 3, qc = q & 7;
        out[ob + (size_t)g * HW + (size_t)(h0 + qr) * Ww + (w0 + qc)] =
            funmap(table[q * NC + g]);
    }
}

extern "C" void kernel_launch(void* const* d_in, const int* in_sizes, int n_in,
                              void* d_out, int out_size, void* d_ws, size_t ws_size,
                              hipStream_t stream) {
    const float* x      = (const float*)d_in[0];
    const float* y      = (const float*)d_in[1];
    const int*   labels = (const int*)d_in[2];
    float*       out    = (float*)d_out;
    (void)in_sizes; (void)n_in; (void)out_size; (void)d_ws; (void)ws_size;

    propnet_fused<<<dim3(NBLK), dim3(BLK), 0, stream>>>(x, y, labels, out);
}